// Round 1
// baseline (818.514 us; speedup 1.0000x reference)
//
#include <hip/hip_runtime.h>
#include <hip/hip_bf16.h>

// ---------------- problem constants ----------------
#define BB     2
#define NN     2065          // N_PATCH + N_TABLE + N_CLS
#define NPAD   2112          // 33*64
#define HH     8
#define DD     64
#define EE     512
#define MROWS  (BB*NN)       // 4130
#define NPATCH 2048
#define NTAB   16
#define SCALEF 0.125f
#define EPSF   1e-6f

typedef __bf16 bf16;
typedef bf16  bf16x8 __attribute__((ext_vector_type(8)));
typedef bf16  bf16x4v __attribute__((ext_vector_type(4)));
typedef float f32x4  __attribute__((ext_vector_type(4)));

#define LDS_STRIDE 72   // 64 + 8 pad bf16 (144 B rows, 16B aligned)

// ---------------- prep kernels ----------------
__global__ __launch_bounds__(256) void k_zero(uint4* __restrict__ p, int n4) {
    int i = blockIdx.x * 256 + threadIdx.x;
    if (i < n4) { uint4 z = {0,0,0,0}; p[i] = z; }
}

__global__ __launch_bounds__(256) void k_cvt(const float* __restrict__ x,
                                             bf16* __restrict__ o, int n4) {
    int i = blockIdx.x * 256 + threadIdx.x;
    if (i < n4) {
        float4 v = ((const float4*)x)[i];
        bf16x4v r;
        r[0] = (bf16)v.x; r[1] = (bf16)v.y; r[2] = (bf16)v.z; r[3] = (bf16)v.w;
        *(bf16x4v*)(o + 4*(size_t)i) = r;
    }
}

// out[c*512 + k] = in[k*C + c]   (weights have 512 rows)
__global__ __launch_bounds__(256) void k_transcvt(const float* __restrict__ w,
                                                  bf16* __restrict__ o,
                                                  int C, int total) {
    int i = blockIdx.x * 256 + threadIdx.x;
    if (i < total) {
        int k = i & 511, c = i >> 9;
        o[i] = (bf16)w[(size_t)k * C + c];
    }
}

// ---------------- GEMM1: qkv = x @ w_qkv + b ; scatter into Qh/Kh/Vt ----------------
__global__ __launch_bounds__(256) void k_gemm_qkv(
    const bf16* __restrict__ xb, const bf16* __restrict__ wt,
    const float* __restrict__ bias,
    bf16* __restrict__ Qh, bf16* __restrict__ Kh, bf16* __restrict__ Vt)
{
    __shared__ bf16 As[64][LDS_STRIDE];
    __shared__ bf16 Bs[64][LDS_STRIDE];
    int t = threadIdx.x;
    int w = t >> 6, l = t & 63, l15 = l & 15, quad = l >> 4;
    int m0 = blockIdx.y * 64, c0 = blockIdx.x * 64;
    int srow = t >> 2, sseg = (t & 3) * 16;
    f32x4 acc[4] = {};

    for (int kk = 0; kk < 512; kk += 64) {
        {
            int m = m0 + srow;
            uint4 v0 = {0,0,0,0}, v1 = {0,0,0,0};
            if (m < MROWS) {
                const uint4* src = (const uint4*)(xb + (size_t)m*512 + kk + sseg);
                v0 = src[0]; v1 = src[1];
            }
            *(uint4*)&As[srow][sseg]     = v0;
            *(uint4*)&As[srow][sseg + 8] = v1;
            const uint4* bs = (const uint4*)(wt + (size_t)(c0 + srow)*512 + kk + sseg);
            *(uint4*)&Bs[srow][sseg]     = bs[0];
            *(uint4*)&Bs[srow][sseg + 8] = bs[1];
        }
        __syncthreads();
        #pragma unroll
        for (int kh = 0; kh < 2; kh++) {
            bf16x8 a = *(const bf16x8*)&As[w*16 + l15][kh*32 + quad*8];
            #pragma unroll
            for (int c = 0; c < 4; c++) {
                bf16x8 b = *(const bf16x8*)&Bs[c*16 + l15][kh*32 + quad*8];
                acc[c] = __builtin_amdgcn_mfma_f32_16x16x32_bf16(a, b, acc[c], 0, 0, 0);
            }
        }
        __syncthreads();
    }

    int which = c0 >> 9;             // 0=q 1=k 2=v (uniform per block)
    int h = (c0 & 511) >> 6;         // uniform per block
    #pragma unroll
    for (int c = 0; c < 4; c++) {
        int d  = (c0 & 63) + c*16 + l15;   // c0 is mult of 64 -> d = c*16+l15
        float bv = bias[c0 + c*16 + l15];
        #pragma unroll
        for (int r = 0; r < 4; r++) {
            int m = m0 + w*16 + quad*4 + r;
            if (m >= MROWS) continue;
            int b_ = m / NN, n = m - b_ * NN;
            int bh = b_ * 8 + h;
            float v = acc[c][r] + bv;
            if (which == 0)      Qh[(size_t)(bh*NPAD + n)*64 + d] = (bf16)v;
            else if (which == 1) Kh[(size_t)(bh*NPAD + n)*64 + d] = (bf16)v;
            else                 Vt[((size_t)bh*64 + d)*NPAD + n] = (bf16)v;
        }
    }
}

// ---------------- fused attention: QK^T once, stats, A_raw, A, PV ----------------
// Block = 16 query rows (one 16x16 MFMA row-tile), 256 threads = 4 waves.
// Wave w owns key columns [w*528, (w+1)*528) = 33 tiles of 16 keys.
// Scores live in acc[33] (f32x4 per lane) across all phases.
// Segment boundaries align to tiles: wave3 kt<=28 patch (ends exactly at key 2047),
// kt==29 table (2048..2063), kt==30 l15==0 cls (2064), kt>=31 padding.
__global__ __launch_bounds__(256, 2) void k_attn_fused(
    const bf16* __restrict__ Qh, const bf16* __restrict__ Kh,
    const bf16* __restrict__ Vt,
    float* __restrict__ Araw, float* __restrict__ A,
    bf16* __restrict__ attn)
{
    __shared__ bf16 Ps[16][2120];                    // full P row-tile (bf16), +8 pad
    __shared__ bf16 Kw[4][16][LDS_STRIDE];           // per-wave K (then V) tile
    __shared__ float sSP[4][16], sSE[4][16];         // per-wave patch partials
    __shared__ float sT[16], sTE[16], sC[16];        // wave-3 table/cls stats

    int t = threadIdx.x;
    int w = t >> 6, l = t & 63, l15 = l & 15, quad = l >> 4;
    int n0 = blockIdx.x * 16;
    int bh = blockIdx.y;
    int lrow = l >> 2, lseg = (l & 3) * 16;          // staging: row 0..15, 16-elem seg

    // Q fragments: rows n0..n0+15 (lane row = l15), cols quad*8 + kh*32
    const bf16* qrow = Qh + ((size_t)bh * NPAD + n0 + l15) * 64 + quad * 8;
    bf16x8 qa0 = *(const bf16x8*)qrow;
    bf16x8 qa1 = *(const bf16x8*)(qrow + 32);

    // ---- phase 1: QK^T + in-register stats (no barriers; per-wave staging) ----
    const bf16* kbase = Kh + ((size_t)bh * NPAD + w * 528) * 64;
    const uint4* kp = (const uint4*)(kbase + (size_t)lrow * 64 + lseg);
    uint4 p0 = kp[0], p1 = kp[1];

    f32x4 acc[33];
    float sp[4] = {0,0,0,0}, sep[4] = {0,0,0,0};
    float st[4] = {0,0,0,0}, set_[4] = {0,0,0,0}, cv[4] = {0,0,0,0};

    #pragma unroll
    for (int kt = 0; kt < 33; ++kt) {
        *(uint4*)&Kw[w][lrow][lseg]     = p0;
        *(uint4*)&Kw[w][lrow][lseg + 8] = p1;
        if (kt < 32) {   // prefetch next tile while MFMA/epilogue run
            const uint4* np = (const uint4*)(kbase + ((size_t)(kt+1)*16 + lrow) * 64 + lseg);
            p0 = np[0]; p1 = np[1];
        }
        bf16x8 b0 = *(const bf16x8*)&Kw[w][l15][quad*8];
        bf16x8 b1 = *(const bf16x8*)&Kw[w][l15][32 + quad*8];
        f32x4 c = {0,0,0,0};
        c = __builtin_amdgcn_mfma_f32_16x16x32_bf16(qa0, b0, c, 0, 0, 0);
        c = __builtin_amdgcn_mfma_f32_16x16x32_bf16(qa1, b1, c, 0, 0, 0);
        #pragma unroll
        for (int r = 0; r < 4; ++r) {
            float val = c[r] * SCALEF;
            c[r] = val;
            if (w < 3 || kt <= 28)      { sp[r] += val; sep[r]  += __expf(val); }
            else if (kt == 29)          { st[r] += val; set_[r] += __expf(val); }
            else if (kt == 30)          { if (l15 == 0) cv[r] = val; }
            // kt >= 31 on wave 3: padding keys, nothing to accumulate
        }
        acc[kt] = c;
    }

    // reduce over the 16 l15 lanes (quad bits untouched by masks 1,2,4,8)
    #pragma unroll
    for (int r = 0; r < 4; ++r) {
        #pragma unroll
        for (int m = 1; m < 16; m <<= 1) {
            sp[r]  += __shfl_xor(sp[r],  m, 64);
            sep[r] += __shfl_xor(sep[r], m, 64);
        }
    }
    if (w == 3) {
        #pragma unroll
        for (int r = 0; r < 4; ++r) {
            #pragma unroll
            for (int m = 1; m < 16; m <<= 1) {
                st[r]   += __shfl_xor(st[r],   m, 64);
                set_[r] += __shfl_xor(set_[r], m, 64);
                cv[r]   += __shfl_xor(cv[r],   m, 64);
            }
        }
    }
    if (l15 == 0) {
        #pragma unroll
        for (int r = 0; r < 4; ++r) {
            sSP[w][quad*4 + r] = sp[r];
            sSE[w][quad*4 + r] = sep[r];
            if (w == 3) {
                sT [quad*4 + r] = st[r];
                sTE[quad*4 + r] = set_[r];
                sC [quad*4 + r] = cv[r];
            }
        }
    }
    __syncthreads();

    // ---- phase 2: per-row coefficients (every lane, for its 4 rows) ----
    float cp[4], ct[4], cc[4];
    #pragma unroll
    for (int r = 0; r < 4; ++r) {
        int row = quad*4 + r;
        float spt  = sSP[0][row] + sSP[1][row] + sSP[2][row] + sSP[3][row];
        float sept = sSE[0][row] + sSE[1][row] + sSE[2][row] + sSE[3][row];
        float ep = __expf(spt * (1.0f / NPATCH));
        float et = __expf(sT[row] * (1.0f / NTAB));
        float ec = __expf(sC[row]);
        float s  = ep + et + ec;
        cp[r] = ep / (s * (sept     + EPSF));
        ct[r] = et / (s * (sTE[row] + EPSF));
        cc[r] = ec / (s * (ec       + EPSF));
    }

    // ---- phase 3: A_raw / A stores + P deposit (from registers) ----
    int nvalid[4]; size_t rb[4];
    #pragma unroll
    for (int r = 0; r < 4; ++r) {
        int n = n0 + quad*4 + r;
        nvalid[r] = (n < NN);
        rb[r] = ((size_t)(bh * NN + n)) * NN;
    }
    #pragma unroll
    for (int kt = 0; kt < 33; ++kt) {
        int colbase = w * 528 + kt * 16 + l15;
        #pragma unroll
        for (int r = 0; r < 4; ++r) {
            float val = acc[kt][r];
            float av; bool stok;
            if (w < 3 || kt <= 28) { av = __expf(val) * cp[r]; stok = true; }
            else if (kt == 29)     { av = __expf(val) * ct[r]; stok = true; }
            else if (kt == 30)     { av = (l15 == 0) ? __expf(val) * cc[r] : 0.f; stok = (l15 == 0); }
            else                   { av = 0.f; stok = false; }
            Ps[quad*4 + r][colbase] = (bf16)av;
            if (stok && nvalid[r]) {
                Araw[rb[r] + colbase] = val;
                A   [rb[r] + colbase] = av;
            }
        }
    }
    __syncthreads();

    // ---- phase 4: PV (wave w computes d-cols w*16..w*16+15 for all 16 rows) ----
    const bf16* vbase = Vt + ((size_t)bh * 64 + w * 16) * NPAD;
    const uint4* vp = (const uint4*)(vbase + (size_t)lrow * NPAD + lseg);
    uint4 v0 = vp[0], v1 = vp[1];
    f32x4 o = {0,0,0,0};
    for (int nt = 0; nt < 33; ++nt) {
        *(uint4*)&Kw[w][lrow][lseg]     = v0;
        *(uint4*)&Kw[w][lrow][lseg + 8] = v1;
        if (nt < 32) {
            const uint4* np = (const uint4*)(vbase + (size_t)lrow * NPAD + (nt+1)*64 + lseg);
            v0 = np[0]; v1 = np[1];
        }
        bf16x8 pa0 = *(const bf16x8*)&Ps[l15][nt*64 + quad*8];
        bf16x8 pa1 = *(const bf16x8*)&Ps[l15][nt*64 + 32 + quad*8];
        bf16x8 vb0 = *(const bf16x8*)&Kw[w][l15][quad*8];
        bf16x8 vb1 = *(const bf16x8*)&Kw[w][l15][32 + quad*8];
        o = __builtin_amdgcn_mfma_f32_16x16x32_bf16(pa0, vb0, o, 0, 0, 0);
        o = __builtin_amdgcn_mfma_f32_16x16x32_bf16(pa1, vb1, o, 0, 0, 0);
    }
    int b_ = bh >> 3, h = bh & 7;
    #pragma unroll
    for (int r = 0; r < 4; ++r) {
        int n = n0 + quad*4 + r;
        if (n < NN)
            attn[((size_t)(b_ * NN + n)) * 512 + h * 64 + w * 16 + l15] = (bf16)o[r];
    }
}

// ---------------- GEMM2: out = attn @ w_out + b_out ----------------
__global__ __launch_bounds__(256) void k_gemm_out(
    const bf16* __restrict__ attn, const bf16* __restrict__ wt,
    const float* __restrict__ bias, float* __restrict__ out)
{
    __shared__ bf16 As[64][LDS_STRIDE];
    __shared__ bf16 Bs[64][LDS_STRIDE];
    int t = threadIdx.x;
    int w = t >> 6, l = t & 63, l15 = l & 15, quad = l >> 4;
    int m0 = blockIdx.y * 64, c0 = blockIdx.x * 64;
    int srow = t >> 2, sseg = (t & 3) * 16;
    f32x4 acc[4] = {};

    for (int kk = 0; kk < 512; kk += 64) {
        {
            int m = m0 + srow;
            uint4 v0 = {0,0,0,0}, v1 = {0,0,0,0};
            if (m < MROWS) {
                const uint4* src = (const uint4*)(attn + (size_t)m*512 + kk + sseg);
                v0 = src[0]; v1 = src[1];
            }
            *(uint4*)&As[srow][sseg]     = v0;
            *(uint4*)&As[srow][sseg + 8] = v1;
            const uint4* bs = (const uint4*)(wt + (size_t)(c0 + srow)*512 + kk + sseg);
            *(uint4*)&Bs[srow][sseg]     = bs[0];
            *(uint4*)&Bs[srow][sseg + 8] = bs[1];
        }
        __syncthreads();
        #pragma unroll
        for (int kh = 0; kh < 2; kh++) {
            bf16x8 a = *(const bf16x8*)&As[w*16 + l15][kh*32 + quad*8];
            #pragma unroll
            for (int c = 0; c < 4; c++) {
                bf16x8 b = *(const bf16x8*)&Bs[c*16 + l15][kh*32 + quad*8];
                acc[c] = __builtin_amdgcn_mfma_f32_16x16x32_bf16(a, b, acc[c], 0, 0, 0);
            }
        }
        __syncthreads();
    }
    #pragma unroll
    for (int c = 0; c < 4; c++) {
        int col = c0 + c*16 + l15;
        float bv = bias[col];
        #pragma unroll
        for (int r = 0; r < 4; r++) {
            int m = m0 + w*16 + quad*4 + r;
            if (m < MROWS)
                out[(size_t)m*512 + col] = acc[c][r] + bv;
        }
    }
}

// ---------------- launch ----------------
extern "C" void kernel_launch(void* const* d_in, const int* in_sizes, int n_in,
                              void* d_out, int out_size, void* d_ws, size_t ws_size,
                              hipStream_t stream)
{
    const float* x     = (const float*)d_in[0];
    const float* w_qkv = (const float*)d_in[1];
    const float* b_qkv = (const float*)d_in[2];
    const float* w_out = (const float*)d_in[3];
    const float* b_out = (const float*)d_in[4];

    float* out  = (float*)d_out;
    float* A    = out + (size_t)MROWS * 512;            // 2,114,560
    float* Araw = A   + (size_t)BB * HH * NN * NN;      // +68,227,600

    char* ws = (char*)d_ws;
    size_t off = 0;
    auto alloc = [&](size_t bytes) {
        char* p = ws + off;
        off += (bytes + 255) & ~(size_t)255;
        return p;
    };
    bf16*  xb    = (bf16*)alloc((size_t)MROWS * 512 * 2);
    bf16*  wqt   = (bf16*)alloc((size_t)1536 * 512 * 2);
    bf16*  wot   = (bf16*)alloc((size_t)512 * 512 * 2);
    bf16*  Qh    = (bf16*)alloc((size_t)16 * NPAD * 64 * 2);   // contiguous with
    bf16*  Kh    = (bf16*)alloc((size_t)16 * NPAD * 64 * 2);   // Kh, Vt (sizes are
    bf16*  Vt    = (bf16*)alloc((size_t)16 * NPAD * 64 * 2);   // multiples of 256)
    bf16*  attn  = (bf16*)alloc((size_t)MROWS * 512 * 2);
    (void)ws_size; (void)in_sizes; (void)n_in; (void)out_size;

    // zero the padded Q/K/V region (3 contiguous arrays)
    int zero4 = (int)((size_t)3 * 16 * NPAD * 64 * 2 / 16);    // 811,008 uint4
    k_zero<<<dim3((zero4 + 255) / 256), 256, 0, stream>>>((uint4*)Qh, zero4);

    k_cvt<<<dim3((MROWS*512/4 + 255) / 256), 256, 0, stream>>>(x, xb, MROWS*512/4);
    k_transcvt<<<dim3(1536*512/256), 256, 0, stream>>>(w_qkv, wqt, 1536, 1536*512);
    k_transcvt<<<dim3(512*512/256),  256, 0, stream>>>(w_out, wot, 512,  512*512);

    k_gemm_qkv<<<dim3(24, 65), 256, 0, stream>>>(xb, wqt, b_qkv, Qh, Kh, Vt);
    k_attn_fused<<<dim3(130, 16), 256, 0, stream>>>(Qh, Kh, Vt, Araw, A, attn);
    k_gemm_out<<<dim3(8, 65), 256, 0, stream>>>(attn, wot, b_out, out);
}